// Round 12
// baseline (170.355 us; speedup 1.0000x reference)
//
#include <hip/hip_runtime.h>

#define A_DIM 5
#define B_DIM 32768
#define S_DIM 48
#define HID   256
#define LRELU 0.01f
#define BN_EPS 1e-5f

#define LDE 264   // enc LDS leading dim (bf16)

// ws float layout:
//   [0, 30720)      stats partials: 320 blocks x (48 sum + 48 sq)
//   [30720, 31200)  mean[240], rstd[240]
//   [31232, 31744)  sq_parts[512]
//   [31744]         done-counter (int)
//   float 32768+ :  bf16 swizzled weight B-fragments
#define OFF_ENC 0
#define OFF_SEL 16384
#define OFF_KEY 81920
#define OFF_C1  147456
#define OFF_C2  212992

typedef __bf16 bf16x8 __attribute__((ext_vector_type(8)));
typedef float  f32x4  __attribute__((ext_vector_type(4)));

__device__ __forceinline__ unsigned short f2bf(float x) {
    unsigned u = __builtin_bit_cast(unsigned, x);
    unsigned r = (u + 0x7FFFu + ((u >> 16) & 1u)) >> 16;
    return (unsigned short)r;
}
__device__ __forceinline__ unsigned pk2(float lo, float hi) {
    return (unsigned)f2bf(lo) | ((unsigned)f2bf(hi) << 16);
}
__device__ __forceinline__ float bflo(unsigned u) { return __builtin_bit_cast(float, u << 16); }
__device__ __forceinline__ float bfhi(unsigned u) { return __builtin_bit_cast(float, u & 0xffff0000u); }
__device__ __forceinline__ f32x4 mfma16(bf16x8 a, bf16x8 b, f32x4 c) {
    return __builtin_amdgcn_mfma_f32_16x16x32_bf16(a, b, c, 0, 0, 0);
}
// xn tile: [64 rows][64 cols] bf16, row stride 128 B, XOR-swizzled by ((row&7)<<4)
__device__ __forceinline__ int xn_addr(int row, int col) {
    return (row * 128 + col * 2) ^ ((row & 7) << 4);
}

// ---------------- Kernel A: BN partial sums (0..319) + weight prep (320..425) ----------------
__global__ void stats_prep_kernel(const float* __restrict__ states,
                                  const float* __restrict__ W_enc, const float* __restrict__ W_key,
                                  const float* __restrict__ W_sel, const float* __restrict__ W_c1,
                                  const float* __restrict__ W_c2,
                                  float* __restrict__ ws, unsigned short* __restrict__ wswz) {
    const int t = threadIdx.x;
    if (blockIdx.x < 320) {
        const int a = blockIdx.x >> 6;
        const int chunk = blockIdx.x & 63;
        const float* base = states + ((size_t)a * B_DIM + (size_t)chunk * 512) * S_DIM;
        float s0 = 0.f, s1 = 0.f, s2 = 0.f, q0 = 0.f, q1 = 0.f, q2 = 0.f;
        for (int i = 0; i < 96; i += 3) {
            float x0 = base[t + (i + 0) * 256];
            float x1 = base[t + (i + 1) * 256];
            float x2 = base[t + (i + 2) * 256];
            s0 += x0; q0 += x0 * x0;
            s1 += x1; q1 += x1 * x1;
            s2 += x2; q2 += x2 * x2;
        }
        __shared__ float lsum[48], lsq[48];
        if (t < 48) { lsum[t] = 0.f; lsq[t] = 0.f; }
        __syncthreads();
        const int sA = t % 48, sB = (t + 16) % 48, sC = (t + 32) % 48;
        atomicAdd(&lsum[sA], s0); atomicAdd(&lsq[sA], q0);
        atomicAdd(&lsum[sB], s1); atomicAdd(&lsq[sB], q1);
        atomicAdd(&lsum[sC], s2); atomicAdd(&lsq[sC], q2);
        __syncthreads();
        if (t < 48) {
            ws[blockIdx.x * 96 + t] = lsum[t];
            ws[blockIdx.x * 96 + 48 + t] = lsq[t];
        }
        return;
    }
    const int gid = (blockIdx.x - 320) * 256 + t;
    float vals[8];
    unsigned short* dst;
    if (gid < 2048) {                       // W_enc: chunks=16, KS=2, K pad 48->64
        const int lid = gid, lane = lid & 63, fi = lid >> 6;
        const int ks = fi & 1, chunk = fi >> 1;
        const int n = (chunk << 4) + (lane & 15), k0 = ks * 32 + ((lane >> 4) << 3);
#pragma unroll
        for (int j = 0; j < 8; ++j) { int k = k0 + j; vals[j] = (k < 48) ? W_enc[k * 256 + n] : 0.f; }
        dst = wswz + OFF_ENC + (size_t)lid * 8;
    } else if (gid < 10240) {               // W_sel cat
        const int lid = gid - 2048, lane = lid & 63, fi = lid >> 6;
        const int ks = fi & 7, chunk = fi >> 3;
        const int n = (chunk << 4) + (lane & 15), k0 = ks * 32 + ((lane >> 4) << 3);
        const int head = n >> 6, d = n & 63;
#pragma unroll
        for (int j = 0; j < 8; ++j) { int k = k0 + j; vals[j] = W_sel[(head * 256 + k) * 64 + d]; }
        dst = wswz + OFF_SEL + (size_t)lid * 8;
    } else if (gid < 18432) {               // W_key cat
        const int lid = gid - 10240, lane = lid & 63, fi = lid >> 6;
        const int ks = fi & 7, chunk = fi >> 3;
        const int n = (chunk << 4) + (lane & 15), k0 = ks * 32 + ((lane >> 4) << 3);
        const int head = n >> 6, d = n & 63;
#pragma unroll
        for (int j = 0; j < 8; ++j) { int k = k0 + j; vals[j] = W_key[(head * 256 + k) * 64 + d]; }
        dst = wswz + OFF_KEY + (size_t)lid * 8;
    } else if (gid < 26624) {               // W_c1
        const int lid = gid - 18432, lane = lid & 63, fi = lid >> 6;
        const int ks = fi & 7, chunk = fi >> 3;
        const int n = (chunk << 4) + (lane & 15), k0 = ks * 32 + ((lane >> 4) << 3);
#pragma unroll
        for (int j = 0; j < 8; ++j) { int k = k0 + j; vals[j] = W_c1[k * 256 + n]; }
        dst = wswz + OFF_C1 + (size_t)lid * 8;
    } else if (gid < 27136) {               // W_c2: N pad 8->16
        const int lid = gid - 26624, lane = lid & 63, ks = lid >> 6;
        const int n = lane & 15, k0 = ks * 32 + ((lane >> 4) << 3);
#pragma unroll
        for (int j = 0; j < 8; ++j) { int k = k0 + j; vals[j] = (n < 8) ? W_c2[k * 8 + n] : 0.f; }
        dst = wswz + OFF_C2 + (size_t)lid * 8;
    } else return;
#pragma unroll
    for (int j = 0; j < 8; ++j) dst[j] = f2bf(vals[j]);
}

// ---------------- Kernel B: finalize mean/rstd + zero done-counter ----------------
__global__ void stats2_kernel(float* __restrict__ ws) {
    const int t = threadIdx.x;
    if (t == 255) ((int*)ws)[31744] = 0;
    if (t >= 240) return;
    const int a = t / 48, s = t % 48;
    float sum = 0.f, sq = 0.f;
    for (int c = 0; c < 64; ++c) {
        sum += ws[(a * 64 + c) * 96 + s];
        sq  += ws[(a * 64 + c) * 96 + 48 + s];
    }
    const float mean = sum * (1.f / (float)B_DIM);
    const float var  = sq * (1.f / (float)B_DIM) - mean * mean;
    ws[30720 + t] = mean;
    ws[30960 + t] = rsqrtf(var + BN_EPS);
}

// K-loop, B from global with depth-2 register pipeline (A linear LDS, ld=LDE) — R9 version
template<int KS>
__device__ __forceinline__ void gemm_block(const unsigned short* __restrict__ aL,
                                           const unsigned short* __restrict__ bW,
                                           int l15, int lg, int lane, int w,
                                           f32x4 acc[2][4]) {
    const unsigned short* b0p = bW + ((size_t)((w * 2 + 0) * KS) * 64 + lane) * 8;
    const unsigned short* b1p = bW + ((size_t)((w * 2 + 1) * KS) * 64 + lane) * 8;
    bf16x8 cur0 = *(const bf16x8*)(b0p);
    bf16x8 cur1 = *(const bf16x8*)(b1p);
    bf16x8 nxt0 = *(const bf16x8*)(b0p + 512);
    bf16x8 nxt1 = *(const bf16x8*)(b1p + 512);
#pragma unroll
    for (int ks = 0; ks < KS; ++ks) {
        bf16x8 af[4];
#pragma unroll
        for (int rb = 0; rb < 4; ++rb)
            af[rb] = *(const bf16x8*)(aL + (rb * 16 + l15) * LDE + ks * 32 + lg * 8);
        const bf16x8 u0 = cur0, u1 = cur1;
        cur0 = nxt0; cur1 = nxt1;
        if (ks + 2 < KS) {
            nxt0 = *(const bf16x8*)(b0p + (size_t)(ks + 2) * 512);
            nxt1 = *(const bf16x8*)(b1p + (size_t)(ks + 2) * 512);
        }
#pragma unroll
        for (int rb = 0; rb < 4; ++rb)
            acc[0][rb] = mfma16(af[rb], u0, acc[0][rb]);
#pragma unroll
        for (int rb = 0; rb < 4; ++rb)
            acc[1][rb] = mfma16(af[rb], u1, acc[1][rb]);
    }
}

__device__ __forceinline__ void store_tile(unsigned short* __restrict__ dstL, int wn, int l15, int lg,
                                           const f32x4 acc[2][4], float bias0, float bias1, bool dolrelu) {
#pragma unroll
    for (int c = 0; c < 2; ++c) {
        const float bias = c ? bias1 : bias0;
        const int col = wn + c * 16 + l15;
#pragma unroll
        for (int rb = 0; rb < 4; ++rb)
#pragma unroll
            for (int r = 0; r < 4; ++r) {
                const int row = rb * 16 + lg * 4 + r;
                float v = acc[c][rb][r] + bias;
                if (dolrelu) v = v >= 0.f ? v : LRELU * v;
                dstL[row * LDE + col] = f2bf(v);
            }
    }
}

// ---------------- Kernel C: fused main (512 blocks x 512 threads) ----------------
__global__ void __launch_bounds__(512, 4)
main_kernel(const float* __restrict__ states,
            const float* __restrict__ b_enc, const float* __restrict__ b_c1,
            const float* __restrict__ b_c2,
            const unsigned short* __restrict__ wswz,
            const float* __restrict__ meanrstd,
            float* __restrict__ out, float* __restrict__ ws)
{
    extern __shared__ char smem[];
    char* xnB = smem;                                        // 8192 B swizzled
    unsigned short* e1L = (unsigned short*)(smem + 8192);    // 64x264 bf16 = 33792
    unsigned short* e2L = (unsigned short*)(smem + 41984);   // 33792
    float* pbuf = (float*)(smem + 75776);                    // [2][512] f32 = 4096
    float* mrL  = (float*)(smem + 79872);                    // 480 f32

    float* sq_parts = ws + 31232;
    int*   done_ctr = (int*)ws + 31744;

    const int t    = threadIdx.x;
    const int lane = t & 63;
    const int w    = t >> 6;
    const int l15  = lane & 15;
    const int lg   = lane >> 4;
    const int b0   = blockIdx.x * 64;
    const int wn   = w * 32;

    const float benc0 = b_enc[wn + l15], benc1 = b_enc[wn + 16 + l15];
    const float bc10  = b_c1[wn + l15],  bc11  = b_c1[wn + 16 + l15];

    // W_enc B-fragments hoisted (reused 5x)
    bf16x8 encB[2][2];
#pragma unroll
    for (int c = 0; c < 2; ++c)
#pragma unroll
        for (int ks = 0; ks < 2; ++ks)
            encB[c][ks] = *(const bf16x8*)(wswz + OFF_ENC +
                           ((size_t)((w * 2 + c) * 2 + ks) * 64 + lane) * 8);

    if (t < 480) mrL[t] = meanrstd[t];
    for (int i = t; i < 64 * 16; i += 512) {
        const int row = i >> 4, c = 48 + (i & 15);
        *(unsigned short*)(xnB + xn_addr(row, c)) = 0;
    }
    float pf[6];
    {
        const float* sp = states + (size_t)b0 * S_DIM;
#pragma unroll
        for (int j = 0; j < 6; ++j) pf[j] = __builtin_nontemporal_load(sp + t + j * 512);
    }
    __syncthreads();

#define WRITE_XN(A)                                                              \
    {                                                                            \
        _Pragma("unroll")                                                        \
        for (int j = 0; j < 6; ++j) {                                            \
            const int idx = t + j * 512, row = idx / 48, s = idx - row * 48;     \
            const float v = (pf[j] - mrL[(A) * 48 + s]) * mrL[240 + (A) * 48 + s]; \
            *(unsigned short*)(xnB + xn_addr(row, s)) = f2bf(v);                 \
        }                                                                        \
    }
#define LOAD_PF(A)                                                               \
    {                                                                            \
        const float* sp = states + ((size_t)(A) * B_DIM + b0) * S_DIM;           \
        _Pragma("unroll")                                                        \
        for (int j = 0; j < 6; ++j) pf[j] = __builtin_nontemporal_load(sp + t + j * 512); \
    }
#define ENC_GEMM(DST)                                                            \
    {                                                                            \
        f32x4 acc[2][4] = {};                                                    \
        _Pragma("unroll")                                                        \
        for (int ks = 0; ks < 2; ++ks) {                                         \
            bf16x8 af[4];                                                        \
            _Pragma("unroll")                                                    \
            for (int rb = 0; rb < 4; ++rb) {                                     \
                const int row = rb * 16 + l15, col = ks * 32 + lg * 8;           \
                af[rb] = *(const bf16x8*)(xnB + xn_addr(row, col));              \
            }                                                                    \
            _Pragma("unroll")                                                    \
            for (int c = 0; c < 2; ++c)                                          \
                _Pragma("unroll")                                                \
                for (int rb = 0; rb < 4; ++rb)                                   \
                    acc[c][rb] = mfma16(af[rb], encB[c][ks], acc[c][rb]);        \
        }                                                                        \
        store_tile(DST, wn, l15, lg, acc, benc0, benc1, true);                   \
    }

    WRITE_XN(0);
    __syncthreads();

    unsigned selP[16];
    float sqacc = 0.f;

    // P1: enc0 -> e1L ; prefetch a1
    ENC_GEMM(e1L);
    LOAD_PF(1);
    __syncthreads();

    // P2: sel + c1 (back-to-back B streams) ; write xn1
    {
        f32x4 acc2[2][4] = {};
        gemm_block<8>(e1L, wswz + OFF_SEL, l15, lg, lane, w, acc2);
#pragma unroll
        for (int c = 0; c < 2; ++c)
#pragma unroll
            for (int rb = 0; rb < 4; ++rb) {
                selP[(c * 4 + rb) * 2 + 0] = pk2(acc2[c][rb][0], acc2[c][rb][1]);
                selP[(c * 4 + rb) * 2 + 1] = pk2(acc2[c][rb][2], acc2[c][rb][3]);
            }
        f32x4 acc3[2][4] = {};
        gemm_block<8>(e1L, wswz + OFF_C1, l15, lg, lane, w, acc3);
        WRITE_XN(1);
        __syncthreads();                     // all reads of e1L(enc0) done
        store_tile(e1L, wn, l15, lg, acc3, bc10, bc11, true);   // e1L <- h
    }
    __syncthreads();

    // P3: enc1 -> e2L ; prefetch a2
    ENC_GEMM(e2L);
    LOAD_PF(2);
    __syncthreads();

    // P4: c2 (reads e1L = h) ; write xn2
    if (w < 4) {
        f32x4 q = {};
#pragma unroll
        for (int ks = 0; ks < 8; ++ks) {
            bf16x8 af = *(const bf16x8*)(e1L + (w * 16 + l15) * LDE + ks * 32 + lg * 8);
            bf16x8 bf = *(const bf16x8*)(wswz + OFF_C2 + ((size_t)(ks * 64 + lane)) * 8);
            q = mfma16(af, bf, q);
        }
        if (l15 < 8) {
            const float bq = b_c2[l15];
#pragma unroll
            for (int r = 0; r < 4; ++r) {
                const int row = w * 16 + lg * 4 + r;
                __builtin_nontemporal_store(q[r] + bq, &out[(size_t)(b0 + row) * 8 + l15]);
            }
        }
    }
    WRITE_XN(2);
    __syncthreads();

    // P5: enc2 -> e1L ; prefetch a3
    ENC_GEMM(e1L);
    LOAD_PF(3);
    __syncthreads();

#define KEYS_PHASE(AL, PDST)                                                     \
    {                                                                            \
        f32x4 acc2[2][4] = {};                                                   \
        gemm_block<8>(AL, wswz + OFF_KEY, l15, lg, lane, w, acc2);               \
        float p[4][4];                                                           \
        _Pragma("unroll")                                                        \
        for (int rb = 0; rb < 4; ++rb)                                           \
            _Pragma("unroll")                                                    \
            for (int r = 0; r < 4; ++r) p[rb][r] = 0.f;                          \
        _Pragma("unroll")                                                        \
        for (int c = 0; c < 2; ++c)                                              \
            _Pragma("unroll")                                                    \
            for (int rb = 0; rb < 4; ++rb) {                                     \
                const unsigned lo = selP[(c * 4 + rb) * 2 + 0];                  \
                const unsigned hi = selP[(c * 4 + rb) * 2 + 1];                  \
                p[rb][0] += bflo(lo) * acc2[c][rb][0];                           \
                p[rb][1] += bfhi(lo) * acc2[c][rb][1];                           \
                p[rb][2] += bflo(hi) * acc2[c][rb][2];                           \
                p[rb][3] += bfhi(hi) * acc2[c][rb][3];                           \
            }                                                                    \
        _Pragma("unroll")                                                        \
        for (int m = 1; m < 16; m <<= 1)                                         \
            _Pragma("unroll")                                                    \
            for (int rb = 0; rb < 4; ++rb)                                       \
                _Pragma("unroll")                                                \
                for (int r = 0; r < 4; ++r)                                      \
                    p[rb][r] += __shfl_xor(p[rb][r], m);                         \
        if (l15 == 0) {                                                          \
            _Pragma("unroll")                                                    \
            for (int rb = 0; rb < 4; ++rb)                                       \
                _Pragma("unroll")                                                \
                for (int r = 0; r < 4; ++r)                                      \
                    (PDST)[w * 64 + rb * 16 + lg * 4 + r] = p[rb][r];            \
        }                                                                        \
    }
#define FOLD2()                                                                  \
    {                                                                            \
        const float* pb = pbuf + (t >> 8) * 512;                                 \
        const int row = t & 63, k = (t >> 6) & 3;                                \
        const float l = pb[(2 * k) * 64 + row] + pb[(2 * k + 1) * 64 + row];     \
        sqacc += l * l;                                                          \
    }

    // P6: keys-a1 (A = e2L) ; write xn3 ; prefetch a4
    KEYS_PHASE(e2L, pbuf);
    WRITE_XN(3);
    LOAD_PF(4);
    __syncthreads();

    // P7: keys-a2 (A = e1L, B is L2-hot)
    KEYS_PHASE(e1L, pbuf + 512);
    __syncthreads();

    // P8: fold a1,a2 ; enc3 -> e2L
    FOLD2();
    ENC_GEMM(e2L);
    __syncthreads();

    // P9: write xn4
    WRITE_XN(4);
    __syncthreads();

    // P10: enc4 -> e1L
    ENC_GEMM(e1L);
    __syncthreads();

    // P11: keys-a3 (A = e2L)
    KEYS_PHASE(e2L, pbuf);
    __syncthreads();

    // P12: keys-a4 (A = e1L, B L2-hot)
    KEYS_PHASE(e1L, pbuf + 512);
    __syncthreads();

    // P13: fold a3,a4 ; block reduce ; last-block final reduction
    FOLD2();
    float v = sqacc;
#pragma unroll
    for (int m = 1; m < 64; m <<= 1) v += __shfl_xor(v, m);
    __syncthreads();                 // pbuf reads done; reuse as redF
    if (lane == 0) pbuf[w] = v;
    __syncthreads();
    __shared__ int is_last;
    if (t == 0) {
        float s = 0.f;
#pragma unroll
        for (int i = 0; i < 8; ++i) s += pbuf[i];
        sq_parts[blockIdx.x] = s;
        __threadfence();
        is_last = (atomicAdd(done_ctr, 1) == 511);
    }
    __syncthreads();
    if (is_last) {
        __threadfence();
        float part = sq_parts[t];            // 512 threads read 512 parts
        pbuf[t] = part;
        __syncthreads();
        for (int s2 = 256; s2 > 0; s2 >>= 1) {
            if (t < s2) pbuf[t] += pbuf[t + s2];
            __syncthreads();
        }
        if (t == 0)
            out[(size_t)B_DIM * 8] = pbuf[0] * (0.001f / ((float)B_DIM * 4.f));
    }
#undef WRITE_XN
#undef LOAD_PF
#undef ENC_GEMM
#undef KEYS_PHASE
#undef FOLD2
}

extern "C" void kernel_launch(void* const* d_in, const int* in_sizes, int n_in,
                              void* d_out, int out_size, void* d_ws, size_t ws_size,
                              hipStream_t stream) {
    const float* states = (const float*)d_in[0];
    const float* W_enc  = (const float*)d_in[1];
    const float* b_enc  = (const float*)d_in[2];
    const float* W_key  = (const float*)d_in[3];
    const float* W_sel  = (const float*)d_in[4];
    // d_in[5]=W_val, d_in[6]=b_val: dead (multiplied by 0.0 in reference)
    const float* W_c1   = (const float*)d_in[7];
    const float* b_c1   = (const float*)d_in[8];
    const float* W_c2   = (const float*)d_in[9];
    const float* b_c2   = (const float*)d_in[10];
    float* out = (float*)d_out;
    float* ws  = (float*)d_ws;

    float* meanrstd = ws + 30720;
    unsigned short* wswz = (unsigned short*)(ws + 32768);

    stats_prep_kernel<<<426, 256, 0, stream>>>(states, W_enc, W_key, W_sel, W_c1, W_c2,
                                               ws, wswz);
    stats2_kernel<<<1, 256, 0, stream>>>(ws);

    const size_t ldsz = 8192 + 33792 + 33792 + 4096 + 1920; // 81792 B -> 2 blocks/CU
    main_kernel<<<512, 512, ldsz, stream>>>(states, b_enc, b_c1, b_c2, wswz,
                                            meanrstd, out, ws);
}

// Round 13
// 117.856 us; speedup vs baseline: 1.4455x; 1.4455x over previous
//
#include <hip/hip_runtime.h>

#define A_DIM 5
#define B_DIM 32768
#define S_DIM 48
#define HID   256
#define LRELU 0.01f
#define BN_EPS 1e-5f

#define LDE 264   // enc LDS leading dim (bf16)

// ws float layout:
//   [0, 30720)      stats partials: 320 blocks x (48 sum + 48 sq)
//   [30720, 31200)  mean[240], rstd[240]
//   [31232, 31744)  sq_parts[512]
//   [31744]         done-counter (int)
//   float 32768+ :  bf16 swizzled weight B-fragments
#define OFF_ENC 0
#define OFF_SEL 16384
#define OFF_KEY 81920
#define OFF_C1  147456
#define OFF_C2  212992

typedef __bf16 bf16x8 __attribute__((ext_vector_type(8)));
typedef float  f32x4  __attribute__((ext_vector_type(4)));

__device__ __forceinline__ unsigned short f2bf(float x) {
    unsigned u = __builtin_bit_cast(unsigned, x);
    unsigned r = (u + 0x7FFFu + ((u >> 16) & 1u)) >> 16;
    return (unsigned short)r;
}
__device__ __forceinline__ unsigned pk2(float lo, float hi) {
    return (unsigned)f2bf(lo) | ((unsigned)f2bf(hi) << 16);
}
__device__ __forceinline__ float bflo(unsigned u) { return __builtin_bit_cast(float, u << 16); }
__device__ __forceinline__ float bfhi(unsigned u) { return __builtin_bit_cast(float, u & 0xffff0000u); }
__device__ __forceinline__ f32x4 mfma16(bf16x8 a, bf16x8 b, f32x4 c) {
    return __builtin_amdgcn_mfma_f32_16x16x32_bf16(a, b, c, 0, 0, 0);
}
// xn tile: [64 rows][64 cols] bf16, row stride 128 B, XOR-swizzled by ((row&7)<<4)
__device__ __forceinline__ int xn_addr(int row, int col) {
    return (row * 128 + col * 2) ^ ((row & 7) << 4);
}

// ---------------- Kernel A: BN partial sums (0..319) + weight prep (320..425) ----------------
__global__ void stats_prep_kernel(const float* __restrict__ states,
                                  const float* __restrict__ W_enc, const float* __restrict__ W_key,
                                  const float* __restrict__ W_sel, const float* __restrict__ W_c1,
                                  const float* __restrict__ W_c2,
                                  float* __restrict__ ws, unsigned short* __restrict__ wswz) {
    const int t = threadIdx.x;
    if (blockIdx.x < 320) {
        const int a = blockIdx.x >> 6;
        const int chunk = blockIdx.x & 63;
        const float* base = states + ((size_t)a * B_DIM + (size_t)chunk * 512) * S_DIM;
        float s0 = 0.f, s1 = 0.f, s2 = 0.f, q0 = 0.f, q1 = 0.f, q2 = 0.f;
        for (int i = 0; i < 96; i += 3) {
            float x0 = base[t + (i + 0) * 256];
            float x1 = base[t + (i + 1) * 256];
            float x2 = base[t + (i + 2) * 256];
            s0 += x0; q0 += x0 * x0;
            s1 += x1; q1 += x1 * x1;
            s2 += x2; q2 += x2 * x2;
        }
        __shared__ float lsum[48], lsq[48];
        if (t < 48) { lsum[t] = 0.f; lsq[t] = 0.f; }
        __syncthreads();
        const int sA = t % 48, sB = (t + 16) % 48, sC = (t + 32) % 48;
        atomicAdd(&lsum[sA], s0); atomicAdd(&lsq[sA], q0);
        atomicAdd(&lsum[sB], s1); atomicAdd(&lsq[sB], q1);
        atomicAdd(&lsum[sC], s2); atomicAdd(&lsq[sC], q2);
        __syncthreads();
        if (t < 48) {
            ws[blockIdx.x * 96 + t] = lsum[t];
            ws[blockIdx.x * 96 + 48 + t] = lsq[t];
        }
        return;
    }
    const int gid = (blockIdx.x - 320) * 256 + t;
    float vals[8];
    unsigned short* dst;
    if (gid < 2048) {                       // W_enc: chunks=16, KS=2, K pad 48->64
        const int lid = gid, lane = lid & 63, fi = lid >> 6;
        const int ks = fi & 1, chunk = fi >> 1;
        const int n = (chunk << 4) + (lane & 15), k0 = ks * 32 + ((lane >> 4) << 3);
#pragma unroll
        for (int j = 0; j < 8; ++j) { int k = k0 + j; vals[j] = (k < 48) ? W_enc[k * 256 + n] : 0.f; }
        dst = wswz + OFF_ENC + (size_t)lid * 8;
    } else if (gid < 10240) {               // W_sel cat
        const int lid = gid - 2048, lane = lid & 63, fi = lid >> 6;
        const int ks = fi & 7, chunk = fi >> 3;
        const int n = (chunk << 4) + (lane & 15), k0 = ks * 32 + ((lane >> 4) << 3);
        const int head = n >> 6, d = n & 63;
#pragma unroll
        for (int j = 0; j < 8; ++j) { int k = k0 + j; vals[j] = W_sel[(head * 256 + k) * 64 + d]; }
        dst = wswz + OFF_SEL + (size_t)lid * 8;
    } else if (gid < 18432) {               // W_key cat
        const int lid = gid - 10240, lane = lid & 63, fi = lid >> 6;
        const int ks = fi & 7, chunk = fi >> 3;
        const int n = (chunk << 4) + (lane & 15), k0 = ks * 32 + ((lane >> 4) << 3);
        const int head = n >> 6, d = n & 63;
#pragma unroll
        for (int j = 0; j < 8; ++j) { int k = k0 + j; vals[j] = W_key[(head * 256 + k) * 64 + d]; }
        dst = wswz + OFF_KEY + (size_t)lid * 8;
    } else if (gid < 26624) {               // W_c1
        const int lid = gid - 18432, lane = lid & 63, fi = lid >> 6;
        const int ks = fi & 7, chunk = fi >> 3;
        const int n = (chunk << 4) + (lane & 15), k0 = ks * 32 + ((lane >> 4) << 3);
#pragma unroll
        for (int j = 0; j < 8; ++j) { int k = k0 + j; vals[j] = W_c1[k * 256 + n]; }
        dst = wswz + OFF_C1 + (size_t)lid * 8;
    } else if (gid < 27136) {               // W_c2: N pad 8->16
        const int lid = gid - 26624, lane = lid & 63, ks = lid >> 6;
        const int n = lane & 15, k0 = ks * 32 + ((lane >> 4) << 3);
#pragma unroll
        for (int j = 0; j < 8; ++j) { int k = k0 + j; vals[j] = (n < 8) ? W_c2[k * 8 + n] : 0.f; }
        dst = wswz + OFF_C2 + (size_t)lid * 8;
    } else return;
#pragma unroll
    for (int j = 0; j < 8; ++j) dst[j] = f2bf(vals[j]);
}

// ---------------- Kernel B: finalize mean/rstd + zero done-counter ----------------
__global__ void stats2_kernel(float* __restrict__ ws) {
    const int t = threadIdx.x;
    if (t == 255) ((int*)ws)[31744] = 0;
    if (t >= 240) return;
    const int a = t / 48, s = t % 48;
    float sum = 0.f, sq = 0.f;
    for (int c = 0; c < 64; ++c) {
        sum += ws[(a * 64 + c) * 96 + s];
        sq  += ws[(a * 64 + c) * 96 + 48 + s];
    }
    const float mean = sum * (1.f / (float)B_DIM);
    const float var  = sq * (1.f / (float)B_DIM) - mean * mean;
    ws[30720 + t] = mean;
    ws[30960 + t] = rsqrtf(var + BN_EPS);
}

// K-loop, B from global with depth-2 register pipeline (A linear LDS, ld=LDE) — R9 version
template<int KS>
__device__ __forceinline__ void gemm_block(const unsigned short* __restrict__ aL,
                                           const unsigned short* __restrict__ bW,
                                           int l15, int lg, int lane, int w,
                                           f32x4 acc[2][4]) {
    const unsigned short* b0p = bW + ((size_t)((w * 2 + 0) * KS) * 64 + lane) * 8;
    const unsigned short* b1p = bW + ((size_t)((w * 2 + 1) * KS) * 64 + lane) * 8;
    bf16x8 cur0 = *(const bf16x8*)(b0p);
    bf16x8 cur1 = *(const bf16x8*)(b1p);
    bf16x8 nxt0 = *(const bf16x8*)(b0p + 512);
    bf16x8 nxt1 = *(const bf16x8*)(b1p + 512);
#pragma unroll
    for (int ks = 0; ks < KS; ++ks) {
        bf16x8 af[4];
#pragma unroll
        for (int rb = 0; rb < 4; ++rb)
            af[rb] = *(const bf16x8*)(aL + (rb * 16 + l15) * LDE + ks * 32 + lg * 8);
        const bf16x8 u0 = cur0, u1 = cur1;
        cur0 = nxt0; cur1 = nxt1;
        if (ks + 2 < KS) {
            nxt0 = *(const bf16x8*)(b0p + (size_t)(ks + 2) * 512);
            nxt1 = *(const bf16x8*)(b1p + (size_t)(ks + 2) * 512);
        }
#pragma unroll
        for (int rb = 0; rb < 4; ++rb)
            acc[0][rb] = mfma16(af[rb], u0, acc[0][rb]);
#pragma unroll
        for (int rb = 0; rb < 4; ++rb)
            acc[1][rb] = mfma16(af[rb], u1, acc[1][rb]);
    }
}

__device__ __forceinline__ void store_tile(unsigned short* __restrict__ dstL, int wn, int l15, int lg,
                                           const f32x4 acc[2][4], float bias0, float bias1, bool dolrelu) {
#pragma unroll
    for (int c = 0; c < 2; ++c) {
        const float bias = c ? bias1 : bias0;
        const int col = wn + c * 16 + l15;
#pragma unroll
        for (int rb = 0; rb < 4; ++rb)
#pragma unroll
            for (int r = 0; r < 4; ++r) {
                const int row = rb * 16 + lg * 4 + r;
                float v = acc[c][rb][r] + bias;
                if (dolrelu) v = v >= 0.f ? v : LRELU * v;
                dstL[row * LDE + col] = f2bf(v);
            }
    }
}

// ---------------- Kernel C: fused main (512 blocks x 512 threads) ----------------
// NOTE: NO static __shared__ allowed in this kernel — dynamic LDS is exactly
// 81792 B so 2 blocks/CU fit in 160 KiB. A single static int cost 2x occupancy (R12).
__global__ void __launch_bounds__(512, 4)
main_kernel(const float* __restrict__ states,
            const float* __restrict__ b_enc, const float* __restrict__ b_c1,
            const float* __restrict__ b_c2,
            const unsigned short* __restrict__ wswz,
            const float* __restrict__ meanrstd,
            float* __restrict__ out, float* __restrict__ ws)
{
    extern __shared__ char smem[];
    char* xnB = smem;                                        // 8192 B swizzled
    unsigned short* e1L = (unsigned short*)(smem + 8192);    // 64x264 bf16 = 33792
    unsigned short* e2L = (unsigned short*)(smem + 41984);   // 33792
    float* pbuf = (float*)(smem + 75776);                    // [2][512] f32 = 4096
    float* mrL  = (float*)(smem + 79872);                    // 480 f32 (dead after P9)
    int*   lastF = (int*)mrL;                                // epilogue flag (reuses mrL[0])

    float* sq_parts = ws + 31232;
    int*   done_ctr = (int*)ws + 31744;

    const int t    = threadIdx.x;
    const int lane = t & 63;
    const int w    = t >> 6;
    const int l15  = lane & 15;
    const int lg   = lane >> 4;
    const int b0   = blockIdx.x * 64;
    const int wn   = w * 32;

    const float benc0 = b_enc[wn + l15], benc1 = b_enc[wn + 16 + l15];
    const float bc10  = b_c1[wn + l15],  bc11  = b_c1[wn + 16 + l15];

    // W_enc B-fragments hoisted (reused 5x)
    bf16x8 encB[2][2];
#pragma unroll
    for (int c = 0; c < 2; ++c)
#pragma unroll
        for (int ks = 0; ks < 2; ++ks)
            encB[c][ks] = *(const bf16x8*)(wswz + OFF_ENC +
                           ((size_t)((w * 2 + c) * 2 + ks) * 64 + lane) * 8);

    if (t < 480) mrL[t] = meanrstd[t];
    for (int i = t; i < 64 * 16; i += 512) {
        const int row = i >> 4, c = 48 + (i & 15);
        *(unsigned short*)(xnB + xn_addr(row, c)) = 0;
    }
    float pf[6];
    {
        const float* sp = states + (size_t)b0 * S_DIM;
#pragma unroll
        for (int j = 0; j < 6; ++j) pf[j] = __builtin_nontemporal_load(sp + t + j * 512);
    }
    __syncthreads();

#define WRITE_XN(A)                                                              \
    {                                                                            \
        _Pragma("unroll")                                                        \
        for (int j = 0; j < 6; ++j) {                                            \
            const int idx = t + j * 512, row = idx / 48, s = idx - row * 48;     \
            const float v = (pf[j] - mrL[(A) * 48 + s]) * mrL[240 + (A) * 48 + s]; \
            *(unsigned short*)(xnB + xn_addr(row, s)) = f2bf(v);                 \
        }                                                                        \
    }
#define LOAD_PF(A)                                                               \
    {                                                                            \
        const float* sp = states + ((size_t)(A) * B_DIM + b0) * S_DIM;           \
        _Pragma("unroll")                                                        \
        for (int j = 0; j < 6; ++j) pf[j] = __builtin_nontemporal_load(sp + t + j * 512); \
    }
#define ENC_GEMM(DST)                                                            \
    {                                                                            \
        f32x4 acc[2][4] = {};                                                    \
        _Pragma("unroll")                                                        \
        for (int ks = 0; ks < 2; ++ks) {                                         \
            bf16x8 af[4];                                                        \
            _Pragma("unroll")                                                    \
            for (int rb = 0; rb < 4; ++rb) {                                     \
                const int row = rb * 16 + l15, col = ks * 32 + lg * 8;           \
                af[rb] = *(const bf16x8*)(xnB + xn_addr(row, col));              \
            }                                                                    \
            _Pragma("unroll")                                                    \
            for (int c = 0; c < 2; ++c)                                          \
                _Pragma("unroll")                                                \
                for (int rb = 0; rb < 4; ++rb)                                   \
                    acc[c][rb] = mfma16(af[rb], encB[c][ks], acc[c][rb]);        \
        }                                                                        \
        store_tile(DST, wn, l15, lg, acc, benc0, benc1, true);                   \
    }

    WRITE_XN(0);
    __syncthreads();

    unsigned selP[16];
    float sqacc = 0.f;

    // P1: enc0 -> e1L ; prefetch a1
    ENC_GEMM(e1L);
    LOAD_PF(1);
    __syncthreads();

    // P2: sel + c1 (back-to-back B streams) ; write xn1
    {
        f32x4 acc2[2][4] = {};
        gemm_block<8>(e1L, wswz + OFF_SEL, l15, lg, lane, w, acc2);
#pragma unroll
        for (int c = 0; c < 2; ++c)
#pragma unroll
            for (int rb = 0; rb < 4; ++rb) {
                selP[(c * 4 + rb) * 2 + 0] = pk2(acc2[c][rb][0], acc2[c][rb][1]);
                selP[(c * 4 + rb) * 2 + 1] = pk2(acc2[c][rb][2], acc2[c][rb][3]);
            }
        f32x4 acc3[2][4] = {};
        gemm_block<8>(e1L, wswz + OFF_C1, l15, lg, lane, w, acc3);
        WRITE_XN(1);
        __syncthreads();                     // all reads of e1L(enc0) done
        store_tile(e1L, wn, l15, lg, acc3, bc10, bc11, true);   // e1L <- h
    }
    __syncthreads();

    // P3: enc1 -> e2L ; prefetch a2
    ENC_GEMM(e2L);
    LOAD_PF(2);
    __syncthreads();

    // P4: c2 (reads e1L = h) ; write xn2
    if (w < 4) {
        f32x4 q = {};
#pragma unroll
        for (int ks = 0; ks < 8; ++ks) {
            bf16x8 af = *(const bf16x8*)(e1L + (w * 16 + l15) * LDE + ks * 32 + lg * 8);
            bf16x8 bf = *(const bf16x8*)(wswz + OFF_C2 + ((size_t)(ks * 64 + lane)) * 8);
            q = mfma16(af, bf, q);
        }
        if (l15 < 8) {
            const float bq = b_c2[l15];
#pragma unroll
            for (int r = 0; r < 4; ++r) {
                const int row = w * 16 + lg * 4 + r;
                __builtin_nontemporal_store(q[r] + bq, &out[(size_t)(b0 + row) * 8 + l15]);
            }
        }
    }
    WRITE_XN(2);
    __syncthreads();

    // P5: enc2 -> e1L ; prefetch a3
    ENC_GEMM(e1L);
    LOAD_PF(3);
    __syncthreads();

#define KEYS_PHASE(AL, PDST)                                                     \
    {                                                                            \
        f32x4 acc2[2][4] = {};                                                   \
        gemm_block<8>(AL, wswz + OFF_KEY, l15, lg, lane, w, acc2);               \
        float p[4][4];                                                           \
        _Pragma("unroll")                                                        \
        for (int rb = 0; rb < 4; ++rb)                                           \
            _Pragma("unroll")                                                    \
            for (int r = 0; r < 4; ++r) p[rb][r] = 0.f;                          \
        _Pragma("unroll")                                                        \
        for (int c = 0; c < 2; ++c)                                              \
            _Pragma("unroll")                                                    \
            for (int rb = 0; rb < 4; ++rb) {                                     \
                const unsigned lo = selP[(c * 4 + rb) * 2 + 0];                  \
                const unsigned hi = selP[(c * 4 + rb) * 2 + 1];                  \
                p[rb][0] += bflo(lo) * acc2[c][rb][0];                           \
                p[rb][1] += bfhi(lo) * acc2[c][rb][1];                           \
                p[rb][2] += bflo(hi) * acc2[c][rb][2];                           \
                p[rb][3] += bfhi(hi) * acc2[c][rb][3];                           \
            }                                                                    \
        _Pragma("unroll")                                                        \
        for (int m = 1; m < 16; m <<= 1)                                         \
            _Pragma("unroll")                                                    \
            for (int rb = 0; rb < 4; ++rb)                                       \
                _Pragma("unroll")                                                \
                for (int r = 0; r < 4; ++r)                                      \
                    p[rb][r] += __shfl_xor(p[rb][r], m);                         \
        if (l15 == 0) {                                                          \
            _Pragma("unroll")                                                    \
            for (int rb = 0; rb < 4; ++rb)                                       \
                _Pragma("unroll")                                                \
                for (int r = 0; r < 4; ++r)                                      \
                    (PDST)[w * 64 + rb * 16 + lg * 4 + r] = p[rb][r];            \
        }                                                                        \
    }
#define FOLD2()                                                                  \
    {                                                                            \
        const float* pb = pbuf + (t >> 8) * 512;                                 \
        const int row = t & 63, k = (t >> 6) & 3;                                \
        const float l = pb[(2 * k) * 64 + row] + pb[(2 * k + 1) * 64 + row];     \
        sqacc += l * l;                                                          \
    }

    // P6: keys-a1 (A = e2L) ; write xn3 ; prefetch a4
    KEYS_PHASE(e2L, pbuf);
    WRITE_XN(3);
    LOAD_PF(4);
    __syncthreads();

    // P7: keys-a2 (A = e1L, B is L2-hot)
    KEYS_PHASE(e1L, pbuf + 512);
    __syncthreads();

    // P8: fold a1,a2 ; enc3 -> e2L
    FOLD2();
    ENC_GEMM(e2L);
    __syncthreads();

    // P9: write xn4
    WRITE_XN(4);
    __syncthreads();

    // P10: enc4 -> e1L
    ENC_GEMM(e1L);
    __syncthreads();

    // P11: keys-a3 (A = e2L)
    KEYS_PHASE(e2L, pbuf);
    __syncthreads();

    // P12: keys-a4 (A = e1L, B L2-hot)
    KEYS_PHASE(e1L, pbuf + 512);
    __syncthreads();

    // P13: fold a3,a4 ; block reduce ; last-block final reduction
    FOLD2();
    float v = sqacc;
#pragma unroll
    for (int m = 1; m < 64; m <<= 1) v += __shfl_xor(v, m);
    __syncthreads();                 // pbuf reads done; reuse as redF
    if (lane == 0) pbuf[w] = v;
    __syncthreads();
    if (t == 0) {
        float s = 0.f;
#pragma unroll
        for (int i = 0; i < 8; ++i) s += pbuf[i];
        sq_parts[blockIdx.x] = s;
        __threadfence();
        lastF[0] = (atomicAdd(done_ctr, 1) == 511);
    }
    __syncthreads();
    if (lastF[0]) {
        __threadfence();
        pbuf[t] = sq_parts[t];               // 512 threads read 512 parts
        __syncthreads();
        for (int s2 = 256; s2 > 0; s2 >>= 1) {
            if (t < s2) pbuf[t] += pbuf[t + s2];
            __syncthreads();
        }
        if (t == 0)
            out[(size_t)B_DIM * 8] = pbuf[0] * (0.001f / ((float)B_DIM * 4.f));
    }
#undef WRITE_XN
#undef LOAD_PF
#undef ENC_GEMM
#undef KEYS_PHASE
#undef FOLD2
}

extern "C" void kernel_launch(void* const* d_in, const int* in_sizes, int n_in,
                              void* d_out, int out_size, void* d_ws, size_t ws_size,
                              hipStream_t stream) {
    const float* states = (const float*)d_in[0];
    const float* W_enc  = (const float*)d_in[1];
    const float* b_enc  = (const float*)d_in[2];
    const float* W_key  = (const float*)d_in[3];
    const float* W_sel  = (const float*)d_in[4];
    // d_in[5]=W_val, d_in[6]=b_val: dead (multiplied by 0.0 in reference)
    const float* W_c1   = (const float*)d_in[7];
    const float* b_c1   = (const float*)d_in[8];
    const float* W_c2   = (const float*)d_in[9];
    const float* b_c2   = (const float*)d_in[10];
    float* out = (float*)d_out;
    float* ws  = (float*)d_ws;

    float* meanrstd = ws + 30720;
    unsigned short* wswz = (unsigned short*)(ws + 32768);

    stats_prep_kernel<<<426, 256, 0, stream>>>(states, W_enc, W_key, W_sel, W_c1, W_c2,
                                               ws, wswz);
    stats2_kernel<<<1, 256, 0, stream>>>(ws);

    const size_t ldsz = 8192 + 33792 + 33792 + 4096 + 1920; // 81792 B -> 2 blocks/CU
    main_kernel<<<512, 512, ldsz, stream>>>(states, b_enc, b_c1, b_c2, wswz,
                                            meanrstd, out, ws);
}

// Round 14
// 102.684 us; speedup vs baseline: 1.6590x; 1.1477x over previous
//
#include <hip/hip_runtime.h>

#define A_DIM 5
#define B_DIM 32768
#define S_DIM 48
#define HID   256
#define LRELU 0.01f
#define BN_EPS 1e-5f

#define LDE 264   // enc LDS leading dim (bf16)

// ws float layout:
//   [0, 30720)      stats partials: 320 blocks x (48 sum + 48 sq)
//   [30720, 31200)  mean[240], rstd[240]
//   [31232, 31744)  sq_parts[512]
//   float 32768+ :  bf16 swizzled weight B-fragments
#define OFF_ENC 0
#define OFF_SEL 16384
#define OFF_KEY 81920
#define OFF_C1  147456
#define OFF_C2  212992

typedef __bf16 bf16x8 __attribute__((ext_vector_type(8)));
typedef float  f32x4  __attribute__((ext_vector_type(4)));

__device__ __forceinline__ unsigned short f2bf(float x) {
    unsigned u = __builtin_bit_cast(unsigned, x);
    unsigned r = (u + 0x7FFFu + ((u >> 16) & 1u)) >> 16;
    return (unsigned short)r;
}
__device__ __forceinline__ unsigned pk2(float lo, float hi) {
    return (unsigned)f2bf(lo) | ((unsigned)f2bf(hi) << 16);
}
__device__ __forceinline__ float bflo(unsigned u) { return __builtin_bit_cast(float, u << 16); }
__device__ __forceinline__ float bfhi(unsigned u) { return __builtin_bit_cast(float, u & 0xffff0000u); }
__device__ __forceinline__ f32x4 mfma16(bf16x8 a, bf16x8 b, f32x4 c) {
    return __builtin_amdgcn_mfma_f32_16x16x32_bf16(a, b, c, 0, 0, 0);
}
// xn tile: [64 rows][64 cols] bf16, row stride 128 B, XOR-swizzled by ((row&7)<<4)
__device__ __forceinline__ int xn_addr(int row, int col) {
    return (row * 128 + col * 2) ^ ((row & 7) << 4);
}

// ---------------- Kernel A: BN partial sums (0..319) + weight prep (320..425) ----------------
__global__ void stats_prep_kernel(const float* __restrict__ states,
                                  const float* __restrict__ W_enc, const float* __restrict__ W_key,
                                  const float* __restrict__ W_sel, const float* __restrict__ W_c1,
                                  const float* __restrict__ W_c2,
                                  float* __restrict__ ws, unsigned short* __restrict__ wswz) {
    const int t = threadIdx.x;
    if (blockIdx.x < 320) {
        const int a = blockIdx.x >> 6;
        const int chunk = blockIdx.x & 63;
        const float* base = states + ((size_t)a * B_DIM + (size_t)chunk * 512) * S_DIM;
        float s0 = 0.f, s1 = 0.f, s2 = 0.f, q0 = 0.f, q1 = 0.f, q2 = 0.f;
        for (int i = 0; i < 96; i += 3) {
            float x0 = base[t + (i + 0) * 256];
            float x1 = base[t + (i + 1) * 256];
            float x2 = base[t + (i + 2) * 256];
            s0 += x0; q0 += x0 * x0;
            s1 += x1; q1 += x1 * x1;
            s2 += x2; q2 += x2 * x2;
        }
        __shared__ float lsum[48], lsq[48];
        if (t < 48) { lsum[t] = 0.f; lsq[t] = 0.f; }
        __syncthreads();
        const int sA = t % 48, sB = (t + 16) % 48, sC = (t + 32) % 48;
        atomicAdd(&lsum[sA], s0); atomicAdd(&lsq[sA], q0);
        atomicAdd(&lsum[sB], s1); atomicAdd(&lsq[sB], q1);
        atomicAdd(&lsum[sC], s2); atomicAdd(&lsq[sC], q2);
        __syncthreads();
        if (t < 48) {
            ws[blockIdx.x * 96 + t] = lsum[t];
            ws[blockIdx.x * 96 + 48 + t] = lsq[t];
        }
        return;
    }
    const int gid = (blockIdx.x - 320) * 256 + t;
    float vals[8];
    unsigned short* dst;
    if (gid < 2048) {                       // W_enc: chunks=16, KS=2, K pad 48->64
        const int lid = gid, lane = lid & 63, fi = lid >> 6;
        const int ks = fi & 1, chunk = fi >> 1;
        const int n = (chunk << 4) + (lane & 15), k0 = ks * 32 + ((lane >> 4) << 3);
#pragma unroll
        for (int j = 0; j < 8; ++j) { int k = k0 + j; vals[j] = (k < 48) ? W_enc[k * 256 + n] : 0.f; }
        dst = wswz + OFF_ENC + (size_t)lid * 8;
    } else if (gid < 10240) {               // W_sel cat
        const int lid = gid - 2048, lane = lid & 63, fi = lid >> 6;
        const int ks = fi & 7, chunk = fi >> 3;
        const int n = (chunk << 4) + (lane & 15), k0 = ks * 32 + ((lane >> 4) << 3);
        const int head = n >> 6, d = n & 63;
#pragma unroll
        for (int j = 0; j < 8; ++j) { int k = k0 + j; vals[j] = W_sel[(head * 256 + k) * 64 + d]; }
        dst = wswz + OFF_SEL + (size_t)lid * 8;
    } else if (gid < 18432) {               // W_key cat
        const int lid = gid - 10240, lane = lid & 63, fi = lid >> 6;
        const int ks = fi & 7, chunk = fi >> 3;
        const int n = (chunk << 4) + (lane & 15), k0 = ks * 32 + ((lane >> 4) << 3);
        const int head = n >> 6, d = n & 63;
#pragma unroll
        for (int j = 0; j < 8; ++j) { int k = k0 + j; vals[j] = W_key[(head * 256 + k) * 64 + d]; }
        dst = wswz + OFF_KEY + (size_t)lid * 8;
    } else if (gid < 26624) {               // W_c1
        const int lid = gid - 18432, lane = lid & 63, fi = lid >> 6;
        const int ks = fi & 7, chunk = fi >> 3;
        const int n = (chunk << 4) + (lane & 15), k0 = ks * 32 + ((lane >> 4) << 3);
#pragma unroll
        for (int j = 0; j < 8; ++j) { int k = k0 + j; vals[j] = W_c1[k * 256 + n]; }
        dst = wswz + OFF_C1 + (size_t)lid * 8;
    } else if (gid < 27136) {               // W_c2: N pad 8->16
        const int lid = gid - 26624, lane = lid & 63, ks = lid >> 6;
        const int n = lane & 15, k0 = ks * 32 + ((lane >> 4) << 3);
#pragma unroll
        for (int j = 0; j < 8; ++j) { int k = k0 + j; vals[j] = (n < 8) ? W_c2[k * 8 + n] : 0.f; }
        dst = wswz + OFF_C2 + (size_t)lid * 8;
    } else return;
#pragma unroll
    for (int j = 0; j < 8; ++j) dst[j] = f2bf(vals[j]);
}

// ---------------- Kernel B: finalize mean/rstd ----------------
__global__ void stats2_kernel(float* __restrict__ ws) {
    const int t = threadIdx.x;
    if (t >= 240) return;
    const int a = t / 48, s = t % 48;
    float sum = 0.f, sq = 0.f;
    for (int c = 0; c < 64; ++c) {
        sum += ws[(a * 64 + c) * 96 + s];
        sq  += ws[(a * 64 + c) * 96 + 48 + s];
    }
    const float mean = sum * (1.f / (float)B_DIM);
    const float var  = sq * (1.f / (float)B_DIM) - mean * mean;
    ws[30720 + t] = mean;
    ws[30960 + t] = rsqrtf(var + BN_EPS);
}

// K-loop, B from global with depth-2 register pipeline (A linear LDS, ld=LDE)
template<int KS>
__device__ __forceinline__ void gemm_block(const unsigned short* __restrict__ aL,
                                           const unsigned short* __restrict__ bW,
                                           int l15, int lg, int lane, int w,
                                           f32x4 acc[2][4]) {
    const unsigned short* b0p = bW + ((size_t)((w * 2 + 0) * KS) * 64 + lane) * 8;
    const unsigned short* b1p = bW + ((size_t)((w * 2 + 1) * KS) * 64 + lane) * 8;
    bf16x8 cur0 = *(const bf16x8*)(b0p);
    bf16x8 cur1 = *(const bf16x8*)(b1p);
    bf16x8 nxt0 = *(const bf16x8*)(b0p + 512);
    bf16x8 nxt1 = *(const bf16x8*)(b1p + 512);
#pragma unroll
    for (int ks = 0; ks < KS; ++ks) {
        bf16x8 af[4];
#pragma unroll
        for (int rb = 0; rb < 4; ++rb)
            af[rb] = *(const bf16x8*)(aL + (rb * 16 + l15) * LDE + ks * 32 + lg * 8);
        const bf16x8 u0 = cur0, u1 = cur1;
        cur0 = nxt0; cur1 = nxt1;
        if (ks + 2 < KS) {
            nxt0 = *(const bf16x8*)(b0p + (size_t)(ks + 2) * 512);
            nxt1 = *(const bf16x8*)(b1p + (size_t)(ks + 2) * 512);
        }
#pragma unroll
        for (int rb = 0; rb < 4; ++rb)
            acc[0][rb] = mfma16(af[rb], u0, acc[0][rb]);
#pragma unroll
        for (int rb = 0; rb < 4; ++rb)
            acc[1][rb] = mfma16(af[rb], u1, acc[1][rb]);
    }
}

__device__ __forceinline__ void store_tile(unsigned short* __restrict__ dstL, int wn, int l15, int lg,
                                           const f32x4 acc[2][4], float bias0, float bias1, bool dolrelu) {
#pragma unroll
    for (int c = 0; c < 2; ++c) {
        const float bias = c ? bias1 : bias0;
        const int col = wn + c * 16 + l15;
#pragma unroll
        for (int rb = 0; rb < 4; ++rb)
#pragma unroll
            for (int r = 0; r < 4; ++r) {
                const int row = rb * 16 + lg * 4 + r;
                float v = acc[c][rb][r] + bias;
                if (dolrelu) v = v >= 0.f ? v : LRELU * v;
                dstL[row * LDE + col] = f2bf(v);
            }
    }
}

// ---------------- Kernel C: fused main (512 blocks x 512 threads) ----------------
// NOTE: no static __shared__ here — dynamic LDS is exactly 81792 B so 2 blocks/CU
// fit in 160 KiB (a single static int cost 2x occupancy in R12). No per-block
// device fences (threadfence = L2 writeback sweep, cost ~20% in R13).
__global__ void __launch_bounds__(512, 4)
main_kernel(const float* __restrict__ states,
            const float* __restrict__ b_enc, const float* __restrict__ b_c1,
            const float* __restrict__ b_c2,
            const unsigned short* __restrict__ wswz,
            const float* __restrict__ meanrstd,
            float* __restrict__ out, float* __restrict__ sq_parts)
{
    extern __shared__ char smem[];
    char* xnB = smem;                                        // 8192 B swizzled
    unsigned short* e1L = (unsigned short*)(smem + 8192);    // 64x264 bf16 = 33792
    unsigned short* e2L = (unsigned short*)(smem + 41984);   // 33792
    float* pbuf = (float*)(smem + 75776);                    // [2][512] f32 = 4096
    float* mrL  = (float*)(smem + 79872);                    // 480 f32

    const int t    = threadIdx.x;
    const int lane = t & 63;
    const int w    = t >> 6;
    const int l15  = lane & 15;
    const int lg   = lane >> 4;
    const int b0   = blockIdx.x * 64;
    const int wn   = w * 32;

    const float benc0 = b_enc[wn + l15], benc1 = b_enc[wn + 16 + l15];
    const float bc10  = b_c1[wn + l15],  bc11  = b_c1[wn + 16 + l15];

    // W_enc B-fragments hoisted (reused 5x)
    bf16x8 encB[2][2];
#pragma unroll
    for (int c = 0; c < 2; ++c)
#pragma unroll
        for (int ks = 0; ks < 2; ++ks)
            encB[c][ks] = *(const bf16x8*)(wswz + OFF_ENC +
                           ((size_t)((w * 2 + c) * 2 + ks) * 64 + lane) * 8);

    if (t < 480) mrL[t] = meanrstd[t];
    for (int i = t; i < 64 * 16; i += 512) {
        const int row = i >> 4, c = 48 + (i & 15);
        *(unsigned short*)(xnB + xn_addr(row, c)) = 0;
    }
    float pf[6];
    {
        const float* sp = states + (size_t)b0 * S_DIM;
#pragma unroll
        for (int j = 0; j < 6; ++j) pf[j] = __builtin_nontemporal_load(sp + t + j * 512);
    }
    __syncthreads();

#define WRITE_XN(A)                                                              \
    {                                                                            \
        _Pragma("unroll")                                                        \
        for (int j = 0; j < 6; ++j) {                                            \
            const int idx = t + j * 512, row = idx / 48, s = idx - row * 48;     \
            const float v = (pf[j] - mrL[(A) * 48 + s]) * mrL[240 + (A) * 48 + s]; \
            *(unsigned short*)(xnB + xn_addr(row, s)) = f2bf(v);                 \
        }                                                                        \
    }
#define LOAD_PF(A)                                                               \
    {                                                                            \
        const float* sp = states + ((size_t)(A) * B_DIM + b0) * S_DIM;           \
        _Pragma("unroll")                                                        \
        for (int j = 0; j < 6; ++j) pf[j] = __builtin_nontemporal_load(sp + t + j * 512); \
    }
#define ENC_GEMM(DST)                                                            \
    {                                                                            \
        f32x4 acc[2][4] = {};                                                    \
        _Pragma("unroll")                                                        \
        for (int ks = 0; ks < 2; ++ks) {                                         \
            bf16x8 af[4];                                                        \
            _Pragma("unroll")                                                    \
            for (int rb = 0; rb < 4; ++rb) {                                     \
                const int row = rb * 16 + l15, col = ks * 32 + lg * 8;           \
                af[rb] = *(const bf16x8*)(xnB + xn_addr(row, col));              \
            }                                                                    \
            _Pragma("unroll")                                                    \
            for (int c = 0; c < 2; ++c)                                          \
                _Pragma("unroll")                                                \
                for (int rb = 0; rb < 4; ++rb)                                   \
                    acc[c][rb] = mfma16(af[rb], encB[c][ks], acc[c][rb]);        \
        }                                                                        \
        store_tile(DST, wn, l15, lg, acc, benc0, benc1, true);                   \
    }

    WRITE_XN(0);
    __syncthreads();

    unsigned selP[16];
    float sqacc = 0.f;

    // P1: enc0 -> e1L ; prefetch a1
    ENC_GEMM(e1L);
    LOAD_PF(1);
    __syncthreads();

    // P2: sel + c1 (back-to-back B streams) ; write xn1
    {
        f32x4 acc2[2][4] = {};
        gemm_block<8>(e1L, wswz + OFF_SEL, l15, lg, lane, w, acc2);
#pragma unroll
        for (int c = 0; c < 2; ++c)
#pragma unroll
            for (int rb = 0; rb < 4; ++rb) {
                selP[(c * 4 + rb) * 2 + 0] = pk2(acc2[c][rb][0], acc2[c][rb][1]);
                selP[(c * 4 + rb) * 2 + 1] = pk2(acc2[c][rb][2], acc2[c][rb][3]);
            }
        f32x4 acc3[2][4] = {};
        gemm_block<8>(e1L, wswz + OFF_C1, l15, lg, lane, w, acc3);
        WRITE_XN(1);
        __syncthreads();                     // all reads of e1L(enc0) done
        store_tile(e1L, wn, l15, lg, acc3, bc10, bc11, true);   // e1L <- h
    }
    __syncthreads();

    // P3: enc1 -> e2L ; prefetch a2
    ENC_GEMM(e2L);
    LOAD_PF(2);
    __syncthreads();

    // P4: c2 (reads e1L = h) ; write xn2
    if (w < 4) {
        f32x4 q = {};
#pragma unroll
        for (int ks = 0; ks < 8; ++ks) {
            bf16x8 af = *(const bf16x8*)(e1L + (w * 16 + l15) * LDE + ks * 32 + lg * 8);
            bf16x8 bf = *(const bf16x8*)(wswz + OFF_C2 + ((size_t)(ks * 64 + lane)) * 8);
            q = mfma16(af, bf, q);
        }
        if (l15 < 8) {
            const float bq = b_c2[l15];
#pragma unroll
            for (int r = 0; r < 4; ++r) {
                const int row = w * 16 + lg * 4 + r;
                __builtin_nontemporal_store(q[r] + bq, &out[(size_t)(b0 + row) * 8 + l15]);
            }
        }
    }
    WRITE_XN(2);
    __syncthreads();

    // P5: enc2 -> e1L ; prefetch a3
    ENC_GEMM(e1L);
    LOAD_PF(3);
    __syncthreads();

#define KEYS_PHASE(AL, PDST)                                                     \
    {                                                                            \
        f32x4 acc2[2][4] = {};                                                   \
        gemm_block<8>(AL, wswz + OFF_KEY, l15, lg, lane, w, acc2);               \
        float p[4][4];                                                           \
        _Pragma("unroll")                                                        \
        for (int rb = 0; rb < 4; ++rb)                                           \
            _Pragma("unroll")                                                    \
            for (int r = 0; r < 4; ++r) p[rb][r] = 0.f;                          \
        _Pragma("unroll")                                                        \
        for (int c = 0; c < 2; ++c)                                              \
            _Pragma("unroll")                                                    \
            for (int rb = 0; rb < 4; ++rb) {                                     \
                const unsigned lo = selP[(c * 4 + rb) * 2 + 0];                  \
                const unsigned hi = selP[(c * 4 + rb) * 2 + 1];                  \
                p[rb][0] += bflo(lo) * acc2[c][rb][0];                           \
                p[rb][1] += bfhi(lo) * acc2[c][rb][1];                           \
                p[rb][2] += bflo(hi) * acc2[c][rb][2];                           \
                p[rb][3] += bfhi(hi) * acc2[c][rb][3];                           \
            }                                                                    \
        _Pragma("unroll")                                                        \
        for (int m = 1; m < 16; m <<= 1)                                         \
            _Pragma("unroll")                                                    \
            for (int rb = 0; rb < 4; ++rb)                                       \
                _Pragma("unroll")                                                \
                for (int r = 0; r < 4; ++r)                                      \
                    p[rb][r] += __shfl_xor(p[rb][r], m);                         \
        if (l15 == 0) {                                                          \
            _Pragma("unroll")                                                    \
            for (int rb = 0; rb < 4; ++rb)                                       \
                _Pragma("unroll")                                                \
                for (int r = 0; r < 4; ++r)                                      \
                    (PDST)[w * 64 + rb * 16 + lg * 4 + r] = p[rb][r];            \
        }                                                                        \
    }
#define FOLD2()                                                                  \
    {                                                                            \
        const float* pb = pbuf + (t >> 8) * 512;                                 \
        const int row = t & 63, k = (t >> 6) & 3;                                \
        const float l = pb[(2 * k) * 64 + row] + pb[(2 * k + 1) * 64 + row];     \
        sqacc += l * l;                                                          \
    }

    // P6: keys-a1 (A = e2L) ; write xn3 ; prefetch a4
    KEYS_PHASE(e2L, pbuf);
    WRITE_XN(3);
    LOAD_PF(4);
    __syncthreads();

    // P7: keys-a2 (A = e1L, B is L2-hot)
    KEYS_PHASE(e1L, pbuf + 512);
    __syncthreads();

    // P8: fold a1,a2 ; enc3 -> e2L
    FOLD2();
    ENC_GEMM(e2L);
    __syncthreads();

    // P9: write xn4
    WRITE_XN(4);
    __syncthreads();

    // P10: enc4 -> e1L
    ENC_GEMM(e1L);
    __syncthreads();

    // P11: keys-a3 (A = e2L)
    KEYS_PHASE(e2L, pbuf);
    __syncthreads();

    // P12: keys-a4 (A = e1L, B L2-hot)
    KEYS_PHASE(e1L, pbuf + 512);
    __syncthreads();

    // P13: fold a3,a4 ; block reduce
    FOLD2();
    float v = sqacc;
#pragma unroll
    for (int m = 1; m < 64; m <<= 1) v += __shfl_xor(v, m);
    __syncthreads();                 // pbuf reads done; reuse as redF
    if (lane == 0) pbuf[w] = v;
    __syncthreads();
    if (t == 0) {
        float s = 0.f;
#pragma unroll
        for (int i = 0; i < 8; ++i) s += pbuf[i];
        sq_parts[blockIdx.x] = s;
    }
#undef WRITE_XN
#undef LOAD_PF
#undef ENC_GEMM
#undef KEYS_PHASE
#undef FOLD2
}

// ---------------- Kernel D: final reg reduce ----------------
__global__ void reduce_reg_kernel(const float* __restrict__ sq_parts, float* __restrict__ out_reg) {
    __shared__ float red[256];
    const int t = threadIdx.x;
    red[t] = sq_parts[t] + sq_parts[t + 256];
    __syncthreads();
    for (int s = 128; s > 0; s >>= 1) {
        if (t < s) red[t] += red[t + s];
        __syncthreads();
    }
    if (t == 0) out_reg[0] = red[0] * (0.001f / ((float)B_DIM * 4.f));
}

extern "C" void kernel_launch(void* const* d_in, const int* in_sizes, int n_in,
                              void* d_out, int out_size, void* d_ws, size_t ws_size,
                              hipStream_t stream) {
    const float* states = (const float*)d_in[0];
    const float* W_enc  = (const float*)d_in[1];
    const float* b_enc  = (const float*)d_in[2];
    const float* W_key  = (const float*)d_in[3];
    const float* W_sel  = (const float*)d_in[4];
    // d_in[5]=W_val, d_in[6]=b_val: dead (multiplied by 0.0 in reference)
    const float* W_c1   = (const float*)d_in[7];
    const float* b_c1   = (const float*)d_in[8];
    const float* W_c2   = (const float*)d_in[9];
    const float* b_c2   = (const float*)d_in[10];
    float* out = (float*)d_out;
    float* ws  = (float*)d_ws;

    float* meanrstd = ws + 30720;
    float* sq_parts = ws + 31232;
    unsigned short* wswz = (unsigned short*)(ws + 32768);

    stats_prep_kernel<<<426, 256, 0, stream>>>(states, W_enc, W_key, W_sel, W_c1, W_c2,
                                               ws, wswz);
    stats2_kernel<<<1, 256, 0, stream>>>(ws);

    const size_t ldsz = 8192 + 33792 + 33792 + 4096 + 1920; // 81792 B -> 2 blocks/CU
    main_kernel<<<512, 512, ldsz, stream>>>(states, b_enc, b_c1, b_c2, wswz,
                                            meanrstd, out, sq_parts);
    reduce_reg_kernel<<<1, 256, 0, stream>>>(sq_parts, out + (size_t)B_DIM * 8);
}